// Round 3
// baseline (129.480 us; speedup 1.0000x reference)
//
#include <hip/hip_runtime.h>
#include <math.h>

typedef __attribute__((ext_vector_type(8))) short bf16x8;
typedef __attribute__((ext_vector_type(4))) float f32x4;

#define NTAGS 64

// RNE f32 -> bf16 (bit trick; inputs are finite)
__device__ __forceinline__ short f2bf(float f) {
    unsigned u = __builtin_bit_cast(unsigned, f);
    u += 0x7fffu + ((u >> 16) & 1u);
    return (short)(u >> 16);
}

// ---- prep: normalize prototypes, emit bf16 B-fragment table to ws ----
// ws[e], e = chunk*64 + t : bf16x8 of proto t, dims chunk*8 .. chunk*8+7
__global__ __launch_bounds__(256)
void lcl_prep(const float* __restrict__ lemb, bf16x8* __restrict__ ws)
{
    __shared__ float part[4][NTAGS];
    __shared__ float scl[NTAGS];
    const int tid = threadIdx.x;
    const float4* lemb4 = (const float4*)lemb;

    {   // norms (redundant per block, 8 blocks, lemb is 64KB -> cached)
        int t = tid & 63, p = tid >> 6;
        float ss = 0.f;
        #pragma unroll
        for (int j = 0; j < 16; ++j) {
            float4 q = lemb4[t * 64 + p * 16 + j];
            ss += q.x*q.x + q.y*q.y + q.z*q.z + q.w*q.w;
        }
        part[p][t] = ss;
    }
    __syncthreads();
    if (tid < NTAGS) {
        float ss = part[0][tid] + part[1][tid] + part[2][tid] + part[3][tid];
        scl[tid] = 1.0f / fmaxf(sqrtf(ss), 1e-8f);   // cosine_similarity eps
    }
    __syncthreads();

    const int e = blockIdx.x * 256 + tid;            // 2048 entries over 8 blocks
    const int chunk = e >> 6, t = e & 63;
    const float s = scl[t];
    float4 q0 = lemb4[t * 64 + chunk * 2];
    float4 q1 = lemb4[t * 64 + chunk * 2 + 1];
    bf16x8 pk;
    pk[0] = f2bf(q0.x * s); pk[1] = f2bf(q0.y * s);
    pk[2] = f2bf(q0.z * s); pk[3] = f2bf(q0.w * s);
    pk[4] = f2bf(q1.x * s); pk[5] = f2bf(q1.y * s);
    pk[6] = f2bf(q1.z * s); pk[7] = f2bf(q1.w * s);
    ws[e] = pk;
}

// ---- main: one 16-row tile per wave ----
__global__ __launch_bounds__(512, 4)
void lcl_main(const float* __restrict__ feat,
              const int*   __restrict__ labels,
              const bf16x8* __restrict__ protoWS,
              float*       __restrict__ out)
{
    __shared__ bf16x8 protoB[2048];                  // 32 KiB
    const int tid = threadIdx.x;

    #pragma unroll
    for (int i = 0; i < 4; ++i)                      // coalesced 16B copies
        protoB[i * 512 + tid] = protoWS[i * 512 + tid];
    __syncthreads();

    const int lane = tid & 63;
    const int wv   = tid >> 6;
    const int g = lane >> 4;                         // k-group 0..3
    const int r = lane & 15;                         // row (A) / tag-within-ct (B)
    const int r0 = (blockIdx.x * 8 + wv) * 16;

    const float4* feat4 = (const float4*)feat;
    const size_t base = (size_t)(r0 + r) * 64 + g * 2;

    // issue all 16 loads up-front (explicit 64-VGPR budget, independent)
    float4 q[16];
    #pragma unroll
    for (int ks = 0; ks < 8; ++ks) {
        q[2 * ks]     = feat4[base + ks * 8];
        q[2 * ks + 1] = feat4[base + ks * 8 + 1];
    }

    float sq = 0.f;
    #pragma unroll
    for (int i = 0; i < 16; ++i)
        sq = fmaf(q[i].x, q[i].x, fmaf(q[i].y, q[i].y,
             fmaf(q[i].z, q[i].z, fmaf(q[i].w, q[i].w, sq))));

    f32x4 acc[4];
    #pragma unroll
    for (int ct = 0; ct < 4; ++ct) acc[ct] = (f32x4){0.f, 0.f, 0.f, 0.f};

    #pragma unroll
    for (int ks = 0; ks < 8; ++ks) {
        float4 q0 = q[2 * ks], q1 = q[2 * ks + 1];
        bf16x8 af;
        af[0] = f2bf(q0.x); af[1] = f2bf(q0.y);
        af[2] = f2bf(q0.z); af[3] = f2bf(q0.w);
        af[4] = f2bf(q1.x); af[5] = f2bf(q1.y);
        af[6] = f2bf(q1.z); af[7] = f2bf(q1.w);
        const int cbase = (ks * 4 + g) * 64;
        #pragma unroll
        for (int ct = 0; ct < 4; ++ct)
            acc[ct] = __builtin_amdgcn_mfma_f32_16x16x32_bf16(
                          af, protoB[cbase + ct * 16 + r], acc[ct], 0, 0, 0);
    }

    // row norm: lanes {r, r+16, r+32, r+48} hold disjoint k-partials of row r
    sq += __shfl_xor(sq, 16, 64);
    sq += __shfl_xor(sq, 32, 64);
    const float rn = 1.0f / fmaxf(sqrtf(sq), 1e-12f);   // F.normalize eps

    // epilogue: C layout col(tag)=lane&15, row=(lane>>4)*4+reg
    float wloss = 0.f;
    #pragma unroll
    for (int reg = 0; reg < 4; ++reg) {
        const int rowi = g * 4 + reg;
        float rr  = __shfl(rn, rowi, 64);
        int   lbl = labels[r0 + rowi];
        float en = 0.f, pos = 0.f;
        #pragma unroll
        for (int ct = 0; ct < 4; ++ct) {
            float sim = acc[ct][reg] * rr;
            float e   = __expf(2.0f * sim);              // inv_t = 1/0.5
            bool  m   = (lbl == ct * 16 + r);
            en  += m ? 0.f : e;
            pos += m ? 2.0f * sim : 0.f;
        }
        #pragma unroll
        for (int o = 1; o < 16; o <<= 1) {
            en  += __shfl_xor(en,  o, 64);
            pos += __shfl_xor(pos, o, 64);
        }
        wloss += __logf(en) - pos;                       // -log(pos/neg)
    }

    // 4 groups hold 4 disjoint row-subsets; sum groups, add once per wave
    wloss += __shfl_xor(wloss, 16, 64);
    wloss += __shfl_xor(wloss, 32, 64);
    if (lane == 0) atomicAdd(out, wloss);
}

extern "C" void kernel_launch(void* const* d_in, const int* in_sizes, int n_in,
                              void* d_out, int out_size, void* d_ws, size_t ws_size,
                              hipStream_t stream) {
    const float* feat   = (const float*)d_in[0];
    const int*   labels = (const int*)d_in[1];
    const float* lemb   = (const float*)d_in[2];
    float*       out    = (float*)d_out;
    bf16x8*      ws     = (bf16x8*)d_ws;

    hipMemsetAsync(d_out, 0, sizeof(float), stream);
    lcl_prep<<<8, 256, 0, stream>>>(lemb, ws);

    const int nrows = in_sizes[1];                  // B*S = 131072
    const int grid  = nrows / (8 * 16);             // 8 waves/block, 16 rows/wave
    lcl_main<<<grid, 512, 0, stream>>>(feat, labels, ws, out);
}

// Round 4
// 125.901 us; speedup vs baseline: 1.0284x; 1.0284x over previous
//
#include <hip/hip_runtime.h>
#include <math.h>

typedef __attribute__((ext_vector_type(8))) short bf16x8;
typedef __attribute__((ext_vector_type(4))) float f32x4;

#define NTAGS 64

// RNE f32 -> bf16 (bit trick; inputs are finite)
__device__ __forceinline__ short f2bf(float f) {
    unsigned u = __builtin_bit_cast(unsigned, f);
    u += 0x7fffu + ((u >> 16) & 1u);
    return (short)(u >> 16);
}

// ---- prep: normalize prototypes, emit bf16 B-fragment table to ws ----
// ws[e], e = chunk*64 + t : bf16x8 of proto t, dims chunk*8 .. chunk*8+7
__global__ __launch_bounds__(256)
void lcl_prep(const float* __restrict__ lemb, bf16x8* __restrict__ ws)
{
    __shared__ float part[4][NTAGS];
    __shared__ float scl[NTAGS];
    const int tid = threadIdx.x;
    const float4* lemb4 = (const float4*)lemb;

    {
        int t = tid & 63, p = tid >> 6;
        float ss = 0.f;
        #pragma unroll
        for (int j = 0; j < 16; ++j) {
            float4 q = lemb4[t * 64 + p * 16 + j];
            ss += q.x*q.x + q.y*q.y + q.z*q.z + q.w*q.w;
        }
        part[p][t] = ss;
    }
    __syncthreads();
    if (tid < NTAGS) {
        float ss = part[0][tid] + part[1][tid] + part[2][tid] + part[3][tid];
        scl[tid] = 1.0f / fmaxf(sqrtf(ss), 1e-8f);   // cosine_similarity eps
    }
    __syncthreads();

    const int e = blockIdx.x * 256 + tid;            // 2048 entries over 8 blocks
    const int chunk = e >> 6, t = e & 63;
    const float s = scl[t];
    float4 q0 = lemb4[t * 64 + chunk * 2];
    float4 q1 = lemb4[t * 64 + chunk * 2 + 1];
    bf16x8 pk;
    pk[0] = f2bf(q0.x * s); pk[1] = f2bf(q0.y * s);
    pk[2] = f2bf(q0.z * s); pk[3] = f2bf(q0.w * s);
    pk[4] = f2bf(q1.x * s); pk[5] = f2bf(q1.y * s);
    pk[6] = f2bf(q1.z * s); pk[7] = f2bf(q1.w * s);
    ws[e] = pk;
}

// ---- main: one 16-row tile per wave, forced 16-deep load pipeline ----
__global__ __launch_bounds__(512, 4)
void lcl_main(const float* __restrict__ feat,
              const int*   __restrict__ labels,
              const bf16x8* __restrict__ protoWS,
              float*       __restrict__ out)
{
    __shared__ bf16x8 protoB[2048];                  // 32 KiB
    const int tid = threadIdx.x;

    #pragma unroll
    for (int i = 0; i < 4; ++i)                      // coalesced 16B copies
        protoB[i * 512 + tid] = protoWS[i * 512 + tid];
    __syncthreads();                                 // drains proto loads only

    const int lane = tid & 63;
    const int wv   = tid >> 6;
    const int g = lane >> 4;                         // k-group 0..3
    const int r = lane & 15;                         // row (A) / tag-within-ct (B)
    const int r0 = (blockIdx.x * 8 + wv) * 16;

    const float4* feat4 = (const float4*)feat;
    const size_t base = (size_t)(r0 + r) * 64 + g * 2;

    // Issue ALL 16 independent loads, then fence: scheduler cannot sink any
    // load past the barrier -> 16 loads in flight per lane.
    float4 q[16];
    #pragma unroll
    for (int ks = 0; ks < 8; ++ks) {
        q[2 * ks]     = feat4[base + ks * 8];
        q[2 * ks + 1] = feat4[base + ks * 8 + 1];
    }
    const int4 lb = ((const int4*)labels)[(r0 >> 2) + g];  // labels r0+g*4..+3
    __builtin_amdgcn_sched_barrier(0);

    f32x4 acc[4];
    #pragma unroll
    for (int ct = 0; ct < 4; ++ct) acc[ct] = (f32x4){0.f, 0.f, 0.f, 0.f};

    float sq = 0.f;
    #pragma unroll
    for (int ks = 0; ks < 8; ++ks) {                 // consume in issue order:
        float4 q0 = q[2 * ks], q1 = q[2 * ks + 1];   // staggered vmcnt waits
        sq = fmaf(q0.x, q0.x, fmaf(q0.y, q0.y, fmaf(q0.z, q0.z, fmaf(q0.w, q0.w, sq))));
        sq = fmaf(q1.x, q1.x, fmaf(q1.y, q1.y, fmaf(q1.z, q1.z, fmaf(q1.w, q1.w, sq))));
        bf16x8 af;
        af[0] = f2bf(q0.x); af[1] = f2bf(q0.y);
        af[2] = f2bf(q0.z); af[3] = f2bf(q0.w);
        af[4] = f2bf(q1.x); af[5] = f2bf(q1.y);
        af[6] = f2bf(q1.z); af[7] = f2bf(q1.w);
        const int cbase = (ks * 4 + g) * 64;
        #pragma unroll
        for (int ct = 0; ct < 4; ++ct)
            acc[ct] = __builtin_amdgcn_mfma_f32_16x16x32_bf16(
                          af, protoB[cbase + ct * 16 + r], acc[ct], 0, 0, 0);
    }

    // row norm: lanes {r, r+16, r+32, r+48} hold disjoint k-partials of row r
    sq += __shfl_xor(sq, 16, 64);
    sq += __shfl_xor(sq, 32, 64);
    const float rn = 1.0f / fmaxf(sqrtf(sq), 1e-12f);   // F.normalize eps

    // epilogue: C layout col(tag)=lane&15, row=(lane>>4)*4+reg
    float wloss = 0.f;
    #pragma unroll
    for (int reg = 0; reg < 4; ++reg) {
        const int rowi = g * 4 + reg;
        float rr  = __shfl(rn, rowi, 64);
        const int lbl = (reg == 0) ? lb.x : (reg == 1) ? lb.y : (reg == 2) ? lb.z : lb.w;
        float en = 0.f, pos = 0.f;
        #pragma unroll
        for (int ct = 0; ct < 4; ++ct) {
            float sim = acc[ct][reg] * rr;
            float e   = __expf(2.0f * sim);              // inv_t = 1/0.5
            bool  m   = (lbl == ct * 16 + r);
            en  += m ? 0.f : e;
            pos += m ? 2.0f * sim : 0.f;
        }
        #pragma unroll
        for (int o = 1; o < 16; o <<= 1) {
            en  += __shfl_xor(en,  o, 64);
            pos += __shfl_xor(pos, o, 64);
        }
        wloss += __logf(en) - pos;                       // -log(pos/neg)
    }

    // 4 groups hold 4 disjoint row-subsets; sum groups, add once per wave
    wloss += __shfl_xor(wloss, 16, 64);
    wloss += __shfl_xor(wloss, 32, 64);
    if (lane == 0) atomicAdd(out, wloss);
}

extern "C" void kernel_launch(void* const* d_in, const int* in_sizes, int n_in,
                              void* d_out, int out_size, void* d_ws, size_t ws_size,
                              hipStream_t stream) {
    const float* feat   = (const float*)d_in[0];
    const int*   labels = (const int*)d_in[1];
    const float* lemb   = (const float*)d_in[2];
    float*       out    = (float*)d_out;
    bf16x8*      ws     = (bf16x8*)d_ws;

    hipMemsetAsync(d_out, 0, sizeof(float), stream);
    lcl_prep<<<8, 256, 0, stream>>>(lemb, ws);

    const int nrows = in_sizes[1];                  // B*S = 131072
    const int grid  = nrows / (8 * 16);             // 8 waves/block, 16 rows/wave
    lcl_main<<<grid, 512, 0, stream>>>(feat, labels, ws, out);
}

// Round 5
// 34.352 us; speedup vs baseline: 3.7692x; 3.6650x over previous
//
#include <hip/hip_runtime.h>
#include <math.h>

typedef __attribute__((ext_vector_type(8))) short bf16x8;
typedef __attribute__((ext_vector_type(4))) float f32x4;

#define NTAGS 64

// RNE f32 -> bf16 (bit trick; inputs are finite)
__device__ __forceinline__ short f2bf(float f) {
    unsigned u = __builtin_bit_cast(unsigned, f);
    u += 0x7fffu + ((u >> 16) & 1u);
    return (short)(u >> 16);
}

// ---- prep: normalize prototypes, emit bf16 B-fragment table to ws ----
// ws[e], e = chunk*64 + t : bf16x8 of proto t, dims chunk*8 .. chunk*8+7
__global__ __launch_bounds__(256)
void lcl_prep(const float* __restrict__ lemb, bf16x8* __restrict__ ws)
{
    __shared__ float part[4][NTAGS];
    __shared__ float scl[NTAGS];
    const int tid = threadIdx.x;
    const float4* lemb4 = (const float4*)lemb;

    {
        int t = tid & 63, p = tid >> 6;
        float ss = 0.f;
        #pragma unroll
        for (int j = 0; j < 16; ++j) {
            float4 q = lemb4[t * 64 + p * 16 + j];
            ss += q.x*q.x + q.y*q.y + q.z*q.z + q.w*q.w;
        }
        part[p][t] = ss;
    }
    __syncthreads();
    if (tid < NTAGS) {
        float ss = part[0][tid] + part[1][tid] + part[2][tid] + part[3][tid];
        scl[tid] = 1.0f / fmaxf(sqrtf(ss), 1e-8f);   // cosine_similarity eps
    }
    __syncthreads();

    const int e = blockIdx.x * 256 + tid;            // 2048 entries over 8 blocks
    const int chunk = e >> 6, t = e & 63;
    const float s = scl[t];
    float4 q0 = lemb4[t * 64 + chunk * 2];
    float4 q1 = lemb4[t * 64 + chunk * 2 + 1];
    bf16x8 pk;
    pk[0] = f2bf(q0.x * s); pk[1] = f2bf(q0.y * s);
    pk[2] = f2bf(q0.z * s); pk[3] = f2bf(q0.w * s);
    pk[4] = f2bf(q1.x * s); pk[5] = f2bf(q1.y * s);
    pk[6] = f2bf(q1.z * s); pk[7] = f2bf(q1.w * s);
    ws[e] = pk;
}

// ---- main: one 16-row tile per wave; per-block partial, NO global atomics ----
__global__ __launch_bounds__(512, 4)
void lcl_main(const float* __restrict__ feat,
              const int*   __restrict__ labels,
              const bf16x8* __restrict__ protoWS,
              float*       __restrict__ blockPart)
{
    __shared__ bf16x8 protoB[2048];                  // 32 KiB
    __shared__ float  wsum[8];
    const int tid = threadIdx.x;

    #pragma unroll
    for (int i = 0; i < 4; ++i)                      // coalesced 16B copies
        protoB[i * 512 + tid] = protoWS[i * 512 + tid];
    __syncthreads();

    const int lane = tid & 63;
    const int wv   = tid >> 6;
    const int g = lane >> 4;                         // k-group 0..3
    const int r = lane & 15;                         // row (A) / tag-within-ct (B)
    const int r0 = (blockIdx.x * 8 + wv) * 16;

    const float4* feat4 = (const float4*)feat;
    const size_t base = (size_t)(r0 + r) * 64 + g * 2;

    float4 q[16];
    #pragma unroll
    for (int ks = 0; ks < 8; ++ks) {
        q[2 * ks]     = feat4[base + ks * 8];
        q[2 * ks + 1] = feat4[base + ks * 8 + 1];
    }
    const int4 lb = ((const int4*)labels)[(r0 >> 2) + g];  // labels r0+g*4..+3

    f32x4 acc[4];
    #pragma unroll
    for (int ct = 0; ct < 4; ++ct) acc[ct] = (f32x4){0.f, 0.f, 0.f, 0.f};

    float sq = 0.f;
    #pragma unroll
    for (int ks = 0; ks < 8; ++ks) {
        float4 q0 = q[2 * ks], q1 = q[2 * ks + 1];
        sq = fmaf(q0.x, q0.x, fmaf(q0.y, q0.y, fmaf(q0.z, q0.z, fmaf(q0.w, q0.w, sq))));
        sq = fmaf(q1.x, q1.x, fmaf(q1.y, q1.y, fmaf(q1.z, q1.z, fmaf(q1.w, q1.w, sq))));
        bf16x8 af;
        af[0] = f2bf(q0.x); af[1] = f2bf(q0.y);
        af[2] = f2bf(q0.z); af[3] = f2bf(q0.w);
        af[4] = f2bf(q1.x); af[5] = f2bf(q1.y);
        af[6] = f2bf(q1.z); af[7] = f2bf(q1.w);
        const int cbase = (ks * 4 + g) * 64;
        #pragma unroll
        for (int ct = 0; ct < 4; ++ct)
            acc[ct] = __builtin_amdgcn_mfma_f32_16x16x32_bf16(
                          af, protoB[cbase + ct * 16 + r], acc[ct], 0, 0, 0);
    }

    // row norm: lanes {r, r+16, r+32, r+48} hold disjoint k-partials of row r
    sq += __shfl_xor(sq, 16, 64);
    sq += __shfl_xor(sq, 32, 64);
    const float rn = 1.0f / fmaxf(sqrtf(sq), 1e-12f);   // F.normalize eps

    // epilogue: C layout col(tag)=lane&15, row=(lane>>4)*4+reg
    float wloss = 0.f;
    #pragma unroll
    for (int reg = 0; reg < 4; ++reg) {
        const int rowi = g * 4 + reg;
        float rr  = __shfl(rn, rowi, 64);
        const int lbl = (reg == 0) ? lb.x : (reg == 1) ? lb.y : (reg == 2) ? lb.z : lb.w;
        float en = 0.f, pos = 0.f;
        #pragma unroll
        for (int ct = 0; ct < 4; ++ct) {
            float sim = acc[ct][reg] * rr;
            float e   = __expf(2.0f * sim);              // inv_t = 1/0.5
            bool  m   = (lbl == ct * 16 + r);
            en  += m ? 0.f : e;
            pos += m ? 2.0f * sim : 0.f;
        }
        #pragma unroll
        for (int o = 1; o < 16; o <<= 1) {
            en  += __shfl_xor(en,  o, 64);
            pos += __shfl_xor(pos, o, 64);
        }
        wloss += __logf(en) - pos;                       // -log(pos/neg)
    }

    // groups hold disjoint row-subsets; sum across groups -> wave total
    wloss += __shfl_xor(wloss, 16, 64);
    wloss += __shfl_xor(wloss, 32, 64);
    if (lane == 0) wsum[wv] = wloss;
    __syncthreads();
    if (tid == 0) {
        float b = wsum[0] + wsum[1] + wsum[2] + wsum[3]
                + wsum[4] + wsum[5] + wsum[6] + wsum[7];
        blockPart[blockIdx.x] = b;                       // plain store, no atomic
    }
}

// ---- final: sum 1024 block partials into d_out ----
__global__ __launch_bounds__(256)
void lcl_reduce(const float* __restrict__ part, float* __restrict__ out)
{
    __shared__ float s[4];
    const int tid = threadIdx.x;
    float v = part[tid] + part[tid + 256] + part[tid + 512] + part[tid + 768];
    #pragma unroll
    for (int o = 1; o < 64; o <<= 1) v += __shfl_xor(v, o, 64);
    if ((tid & 63) == 0) s[tid >> 6] = v;
    __syncthreads();
    if (tid == 0) out[0] = s[0] + s[1] + s[2] + s[3];
}

extern "C" void kernel_launch(void* const* d_in, const int* in_sizes, int n_in,
                              void* d_out, int out_size, void* d_ws, size_t ws_size,
                              hipStream_t stream) {
    const float* feat   = (const float*)d_in[0];
    const int*   labels = (const int*)d_in[1];
    const float* lemb   = (const float*)d_in[2];
    float*       out    = (float*)d_out;
    bf16x8*      ws     = (bf16x8*)d_ws;                 // [0,32KB): proto table
    float*       part   = (float*)((char*)d_ws + 32768); // [32KB,36KB): partials

    lcl_prep<<<8, 256, 0, stream>>>(lemb, ws);

    const int nrows = in_sizes[1];                  // B*S = 131072
    const int grid  = nrows / (8 * 16);             // 1024 blocks
    lcl_main<<<grid, 512, 0, stream>>>(feat, labels, ws, part);
    lcl_reduce<<<1, 256, 0, stream>>>(part, out);
}